// Round 5
// baseline (212.345 us; speedup 1.0000x reference)
//
#include <hip/hip_runtime.h>
#include <hip/hip_bf16.h>
#include <math.h>

#define N_DIM 128
#define NH 8
#define DKH 32
#define M_ROWS (N_DIM * N_DIM) // 16384

typedef __attribute__((ext_vector_type(8))) short bf16x8;
typedef __attribute__((ext_vector_type(4))) float f32x4;

__device__ inline ushort f2b(float x) {
    union { __hip_bfloat16 b; ushort u; } c;
    c.b = __float2bfloat16(x);
    return c.u;
}

#define GLDS(src, dst) \
    __builtin_amdgcn_global_load_lds((const __attribute__((address_space(1))) void*)(src), \
                                     (__attribute__((address_space(3))) void*)(dst), 16, 0, 0)

// ---------------------------------------------------------------------------
// Convert the four 256x256 f32 weight matrices to bf16 (packed [4][65536])
// ---------------------------------------------------------------------------
__global__ __launch_bounds__(256) void cvt_w_kernel(const float* __restrict__ w0,
                                                    const float* __restrict__ w1,
                                                    const float* __restrict__ w2,
                                                    const float* __restrict__ w3,
                                                    ushort* __restrict__ out) {
    const int b = blockIdx.x;          // 0..255
    const int m = b >> 6;
    const float* src = (m == 0) ? w0 : (m == 1) ? w1 : (m == 2) ? w2 : w3;
    const int off = (b & 63) * 1024 + threadIdx.x * 4;
    float4 v = *(const float4*)(src + off);
    union { ushort u[4]; short4 s4; } p;
    p.u[0] = f2b(v.x); p.u[1] = f2b(v.y); p.u[2] = f2b(v.z); p.u[3] = f2b(v.w);
    *(short4*)(out + (size_t)m * 65536 + off) = p.s4;
}

// ---------------------------------------------------------------------------
// Convert query/key/value f32 -> bf16 into one contiguous [3][16384*256] buf
// ---------------------------------------------------------------------------
__global__ __launch_bounds__(256) void cvt_a_kernel(const float* __restrict__ q,
                                                    const float* __restrict__ k,
                                                    const float* __restrict__ v,
                                                    ushort* __restrict__ out) {
    const int y = blockIdx.y;
    const float* src = (y == 0) ? q : (y == 1) ? k : v;
    const size_t base = ((size_t)blockIdx.x * 256 + threadIdx.x) * 8;
    float4 a = *(const float4*)(src + base);
    float4 b = *(const float4*)(src + base + 4);
    union { ushort u[8]; int4 v4; } p;
    p.u[0] = f2b(a.x); p.u[1] = f2b(a.y); p.u[2] = f2b(a.z); p.u[3] = f2b(a.w);
    p.u[4] = f2b(b.x); p.u[5] = f2b(b.y); p.u[6] = f2b(b.z); p.u[7] = f2b(b.w);
    *(int4*)(out + (size_t)y * (M_ROWS * 256) + base) = p.v4;
}

// ---------------------------------------------------------------------------
// C[M][256] = A[M][256] @ W[256][256]^T via mfma 16x16x32 bf16, A/W bf16.
// BM=32, BN=256, BK=64, 512 threads = 8 waves (wave w owns cols [w*32,+32)).
// grid = (512, BATCHED?3:1); 2 blocks/CU. LDS rows 128 B, XOR-swizzled
// ((row&7)<<4); staged with global_load_lds using inverse-swizzled source.
// ---------------------------------------------------------------------------
template <bool OBF16, bool BATCHED>
__global__ __launch_bounds__(512) void gemm2(const ushort* __restrict__ Abase,
                                             const ushort* __restrict__ Wbase,
                                             void* __restrict__ Cbase,
                                             float oscale0) {
    __shared__ ushort As[2][32 * 64];    // 4 KB per buf
    __shared__ ushort Ws[2][256 * 64];   // 32 KB per buf
    const int tid = threadIdx.x;
    const int w = tid >> 6, l = tid & 63;
    const int lr = l & 15, g = l >> 4;
    const int row0 = blockIdx.x * 32;

    const ushort* A = Abase;
    const ushort* W = Wbase;
    float oscale = oscale0;
    size_t coff = 0;
    if (BATCHED) {
        const int y = blockIdx.y;
        A += (size_t)y * (M_ROWS * 256);
        W += (size_t)y * 65536;
        coff = (size_t)y * (M_ROWS * 256);
        oscale = (y == 0) ? oscale0 : 1.0f;
    }

    const int lrow = l >> 3;                    // 0..7 (row within 8-row chunk)
    const int kof = ((l & 7) ^ lrow) * 8;       // inverse-swizzled k offset

    auto stage = [&](int t, int buf) {
        const int kbase = t * 64;
#pragma unroll
        for (int i = 0; i < 4; i++) {
            const int chunk = i * 8 + w;        // 0..31 -> W rows [chunk*8, +8)
            GLDS(W + (size_t)(chunk * 8 + lrow) * 256 + kbase + kof,
                 &Ws[buf][chunk * 512]);
        }
        if (w < 4) {                            // A rows [w*8, +8)
            GLDS(A + (size_t)(row0 + w * 8 + lrow) * 256 + kbase + kof,
                 &As[buf][w * 512]);
        }
    };

    f32x4 acc[2][2];
    const f32x4 zero = {0.f, 0.f, 0.f, 0.f};
    acc[0][0] = zero; acc[0][1] = zero; acc[1][0] = zero; acc[1][1] = zero;

    stage(0, 0);
    __syncthreads();

#pragma unroll
    for (int t = 0; t < 4; t++) {
        const int cur = t & 1;
        if (t < 3) stage(t + 1, cur ^ 1);
#pragma unroll
        for (int kk = 0; kk < 2; kk++) {
            bf16x8 a[2], b[2];
#pragma unroll
            for (int fr = 0; fr < 2; fr++) {
                const int r = fr * 16 + lr;
                int byte = r * 128 + kk * 64 + g * 16;
                byte ^= (r & 7) << 4;
                a[fr] = *(const bf16x8*)((const char*)&As[cur][0] + byte);
            }
#pragma unroll
            for (int fc = 0; fc < 2; fc++) {
                const int r = w * 32 + fc * 16 + lr;
                int byte = r * 128 + kk * 64 + g * 16;
                byte ^= (r & 7) << 4;
                b[fc] = *(const bf16x8*)((const char*)&Ws[cur][0] + byte);
            }
#pragma unroll
            for (int fr = 0; fr < 2; fr++)
#pragma unroll
                for (int fc = 0; fc < 2; fc++)
                    acc[fr][fc] = __builtin_amdgcn_mfma_f32_16x16x32_bf16(a[fr], b[fc], acc[fr][fc], 0, 0, 0);
        }
        __syncthreads();
    }

#pragma unroll
    for (int fr = 0; fr < 2; fr++)
#pragma unroll
        for (int fc = 0; fc < 2; fc++)
#pragma unroll
            for (int j = 0; j < 4; j++) {
                const int row = row0 + fr * 16 + g * 4 + j;
                const int col = w * 32 + fc * 16 + lr;
                const float vv = acc[fr][fc][j] * oscale;
                if (OBF16) ((ushort*)Cbase)[coff + (size_t)row * 256 + col] = f2b(vv);
                else       ((float*)Cbase)[(size_t)row * 256 + col] = vv;
            }
}

// ---------------------------------------------------------------------------
// Attention pass. PASS=0: l-half, block=(y,h), rows are x.
//                 PASS=1: r-half + combine, block=(x,h), rows are y.
// Q is pre-scaled by 1/sqrt(32) (folded into projection). Mask bitpacked
// via ballot into LDS. Q/K LDS pitch 40 ushorts (conflict-free frag reads).
// ---------------------------------------------------------------------------
template <int PASS>
__global__ __launch_bounds__(256) void attn_pass(const ushort* __restrict__ qb,
                                                 const ushort* __restrict__ kb,
                                                 const ushort* __restrict__ vb,
                                                 const int* __restrict__ mask,
                                                 float* __restrict__ ml,
                                                 float* __restrict__ sl,
                                                 float* __restrict__ Pl,
                                                 ushort* __restrict__ xb) {
    __shared__ ushort Qs[128 * 40];   // pitch 80 B (pad kills 8-way conflict)
    __shared__ ushort Ks[128 * 40];
    __shared__ ushort Vt[32 * 128];   // [d][z], 256B rows, XOR swizzled
    __shared__ ushort Ats[128 * 128]; // [row][z], 256B rows, XOR swizzled
    __shared__ ulonglong2 Ms[128];    // bitpacked mask rows (128 bits/row)
    __shared__ float mlq[128], slq[128];

    const int tid = threadIdx.x;
    const int fixed = blockIdx.x >> 3; // y (PASS0) or x (PASS1)
    const int h = blockIdx.x & 7;

    int base, stride, mbase, mstride;
    if (PASS == 0) {
        base = (fixed * NH + h) * DKH;
        stride = N_DIM * NH * DKH;
        mbase = fixed * N_DIM;
        mstride = N_DIM * N_DIM;
    } else {
        base = fixed * N_DIM * NH * DKH + h * DKH;
        stride = NH * DKH;
        mbase = fixed * N_DIM * N_DIM;
        mstride = N_DIM;
    }

    if (PASS == 1) {
        if (tid < 128) mlq[tid] = ml[(tid * NH + h) * N_DIM + fixed];
        else           slq[tid - 128] = sl[((tid - 128) * NH + h) * N_DIM + fixed];
    }

    const int w = tid >> 6;
    const int lane = tid & 63;

    // ---- bitpack mask rows: wave w handles rows [w*32, +32) ----
    for (int rr = 0; rr < 32; rr++) {
        const int row = w * 32 + rr;
        const int* mrow = mask + mbase + (size_t)row * mstride;
        unsigned long long lo = __ballot(mrow[lane] != 0);
        unsigned long long hi = __ballot(mrow[64 + lane] != 0);
        if (lane == 0) { Ms[row].x = lo; Ms[row].y = hi; }
    }

    // ---- stage Q, K, Vt (transpose + swizzle) ----
#pragma unroll
    for (int i = 0; i < 2; i++) {
        int idx = tid + i * 256;
        int r = idx >> 2, d0 = (idx & 3) * 8;
        size_t goff = (size_t)base + (size_t)r * stride + d0;
        int4 qv = *(const int4*)(qb + goff);
        *(int4*)&Qs[r * 40 + d0] = qv;
        int4 kv = *(const int4*)(kb + goff);
        *(int4*)&Ks[r * 40 + d0] = kv;
        union { int4 v4; ushort u[8]; } uu;
        uu.v4 = *(const int4*)(vb + goff);
#pragma unroll
        for (int j = 0; j < 8; j++) {
            int d = d0 + j;
            int byte = d * 256 + r * 2;
            byte ^= (d & 7) << 4;
            Vt[byte >> 1] = uu.u[j];
        }
    }
    __syncthreads();

    const int lr = lane & 15;
    const int g = lane >> 4;
    const int rbase = w * 32;

    // ---- S = Q K^T (Q pre-scaled) ----
    bf16x8 aq[2];
#pragma unroll
    for (int fr = 0; fr < 2; fr++)
        aq[fr] = *(const bf16x8*)&Qs[(rbase + fr * 16 + lr) * 40 + g * 8];

    f32x4 s[2][8];
    const f32x4 zero = {0.f, 0.f, 0.f, 0.f};
#pragma unroll
    for (int fc = 0; fc < 8; fc++) {
        bf16x8 bk = *(const bf16x8*)&Ks[(fc * 16 + lr) * 40 + g * 8];
#pragma unroll
        for (int fr = 0; fr < 2; fr++)
            s[fr][fc] = __builtin_amdgcn_mfma_f32_16x16x32_bf16(aq[fr], bk, zero, 0, 0, 0);
    }

    // ---- mask (bitpacked), row max, exp, row sum, att->LDS(bf16) ----
    float mx[2][4], sm[2][4];
#pragma unroll
    for (int fr = 0; fr < 2; fr++) {
#pragma unroll
        for (int j = 0; j < 4; j++) {
            const int row = rbase + fr * 16 + g * 4 + j;
            const ulonglong2 mb = Ms[row];
            const unsigned long long mls = mb.x >> lr;
            const unsigned long long mhs = mb.y >> lr;
            float mmax = -3.0e38f;
#pragma unroll
            for (int fc = 0; fc < 8; fc++) {
                const int bit = (int)(((fc < 4 ? mls : mhs) >> ((fc & 3) * 16)) & 1ull);
                float val = bit ? -1.0e9f : s[fr][fc][j];
                s[fr][fc][j] = val;
                mmax = fmaxf(mmax, val);
            }
            mmax = fmaxf(mmax, __shfl_xor(mmax, 1));
            mmax = fmaxf(mmax, __shfl_xor(mmax, 2));
            mmax = fmaxf(mmax, __shfl_xor(mmax, 4));
            mmax = fmaxf(mmax, __shfl_xor(mmax, 8));
            float ssum = 0.f;
#pragma unroll
            for (int fc = 0; fc < 8; fc++) {
                const int col = fc * 16 + lr;
                float e = __expf(s[fr][fc][j] - mmax);
                ssum += e;
                int byte = row * 256 + col * 2;
                byte ^= (row & 7) << 4;
                Ats[byte >> 1] = f2b(e);
            }
            ssum += __shfl_xor(ssum, 1);
            ssum += __shfl_xor(ssum, 2);
            ssum += __shfl_xor(ssum, 4);
            ssum += __shfl_xor(ssum, 8);
            mx[fr][j] = mmax;
            sm[fr][j] = ssum;
        }
    }
    __syncthreads();

    // ---- P = att @ V ----
    f32x4 p[2][2];
    p[0][0] = zero; p[0][1] = zero; p[1][0] = zero; p[1][1] = zero;
#pragma unroll
    for (int ks = 0; ks < 4; ks++) {
        bf16x8 pa[2];
#pragma unroll
        for (int fr = 0; fr < 2; fr++) {
            const int row = rbase + fr * 16 + lr;
            int byte = row * 256 + ks * 64 + g * 16;
            byte ^= (row & 7) << 4;
            pa[fr] = *(const bf16x8*)&Ats[byte >> 1];
        }
#pragma unroll
        for (int fc = 0; fc < 2; fc++) {
            const int rd = fc * 16 + lr;
            int byte = rd * 256 + ks * 64 + g * 16;
            byte ^= (rd & 7) << 4;
            bf16x8 vbf = *(const bf16x8*)&Vt[byte >> 1];
#pragma unroll
            for (int fr = 0; fr < 2; fr++)
                p[fr][fc] = __builtin_amdgcn_mfma_f32_16x16x32_bf16(pa[fr], vbf, p[fr][fc], 0, 0, 0);
        }
    }

    // ---- epilogue ----
    if (PASS == 0) {
#pragma unroll
        for (int fr = 0; fr < 2; fr++) {
#pragma unroll
            for (int j = 0; j < 4; j++) {
                const int row = rbase + fr * 16 + g * 4 + j;
                if (lr == 0) {
                    ml[(fixed * NH + h) * N_DIM + row] = mx[fr][j];
                    sl[(fixed * NH + h) * N_DIM + row] = sm[fr][j];
                }
#pragma unroll
                for (int fc = 0; fc < 2; fc++) {
                    const int d = fc * 16 + lr;
                    Pl[((size_t)(fixed * NH + h) * N_DIM + row) * DKH + d] = p[fr][fc][j];
                }
            }
        }
    } else {
#pragma unroll
        for (int fr = 0; fr < 2; fr++) {
#pragma unroll
            for (int j = 0; j < 4; j++) {
                const int row = rbase + fr * 16 + g * 4 + j;
                const float mr = mx[fr][j], sr = sm[fr][j];
                const float mlv = mlq[row], slv = slq[row];
                const float m = fmaxf(mr, mlv);
                const float cr = __expf(mr - m), cl = __expf(mlv - m);
                const float inv = 1.0f / (sr * cr + slv * cl);
#pragma unroll
                for (int fc = 0; fc < 2; fc++) {
                    const int d = fc * 16 + lr;
                    const float plv = Pl[((size_t)(row * NH + h) * N_DIM + fixed) * DKH + d];
                    const float o = (p[fr][fc][j] * cr + plv * cl) * inv;
                    xb[((size_t)fixed * N_DIM + row) * 256 + h * DKH + d] = f2b(o);
                }
            }
        }
    }
}

extern "C" void kernel_launch(void* const* d_in, const int* in_sizes, int n_in,
                              void* d_out, int out_size, void* d_ws, size_t ws_size,
                              hipStream_t stream) {
    const float* query = (const float*)d_in[0];
    const float* key_t = (const float*)d_in[1];
    const float* value = (const float*)d_in[2];
    const int*   mask  = (const int*)d_in[3];
    const float* Wq    = (const float*)d_in[4];
    const float* Wk    = (const float*)d_in[5];
    const float* Wv    = (const float*)d_in[6];
    const float* Wo    = (const float*)d_in[7];

    const size_t MB = 1024 * 1024;
    char* ws = (char*)d_ws;
    ushort* af = (ushort*)ws;                       // 24 MB: bf16 q/k/v inputs
    ushort* qb = (ushort*)(ws + 24 * MB);           // 8 MB (projections, contiguous)
    ushort* kb = (ushort*)(ws + 32 * MB);
    ushort* vb = (ushort*)(ws + 40 * MB);
    ushort* xb = (ushort*)(ws + 48 * MB);           // 8 MB
    float*  Pl = (float*)(ws + 56 * MB);            // 16 MB
    float*  ml = (float*)(ws + 72 * MB);            // 512 KB
    float*  sl = (float*)(ws + 72 * MB + 512 * 1024); // 512 KB
    ushort* Wb = (ushort*)(ws + 73 * MB);           // 512 KB

    const float qscale = 0.17677669529663687f; // 1/sqrt(32)

    cvt_w_kernel<<<256, 256, 0, stream>>>(Wq, Wk, Wv, Wo, Wb);
    cvt_a_kernel<<<dim3(2048, 3), 256, 0, stream>>>(query, key_t, value, af);
    gemm2<true, true><<<dim3(M_ROWS / 32, 3), 512, 0, stream>>>(af, Wb, qb, qscale);
    attn_pass<0><<<N_DIM * NH, 256, 0, stream>>>(qb, kb, vb, mask, ml, sl, Pl, xb);
    attn_pass<1><<<N_DIM * NH, 256, 0, stream>>>(qb, kb, vb, mask, ml, sl, Pl, xb);
    gemm2<false, false><<<dim3(M_ROWS / 32, 1), 512, 0, stream>>>(xb, Wb + 3 * 65536, d_out, 1.0f);
}

// Round 6
// 169.273 us; speedup vs baseline: 1.2545x; 1.2545x over previous
//
#include <hip/hip_runtime.h>
#include <hip/hip_bf16.h>
#include <math.h>

#define N_DIM 128
#define NH 8
#define DKH 32
#define M_ROWS (N_DIM * N_DIM) // 16384

typedef __attribute__((ext_vector_type(8))) short bf16x8;
typedef __attribute__((ext_vector_type(4))) float f32x4;

__device__ inline ushort f2b(float x) {
    union { __hip_bfloat16 b; ushort u; } c;
    c.b = __float2bfloat16(x);
    return c.u;
}

#define GLDS(src, dst) \
    __builtin_amdgcn_global_load_lds((const __attribute__((address_space(1))) void*)(src), \
                                     (__attribute__((address_space(3))) void*)(dst), 16, 0, 0)

// ---------------------------------------------------------------------------
// Convert the four 256x256 f32 weight matrices to bf16 (packed [4][65536])
// ---------------------------------------------------------------------------
__global__ __launch_bounds__(256) void cvt_w_kernel(const float* __restrict__ w0,
                                                    const float* __restrict__ w1,
                                                    const float* __restrict__ w2,
                                                    const float* __restrict__ w3,
                                                    ushort* __restrict__ out) {
    const int b = blockIdx.x;          // 0..255
    const int m = b >> 6;
    const float* src = (m == 0) ? w0 : (m == 1) ? w1 : (m == 2) ? w2 : w3;
    const int off = (b & 63) * 1024 + threadIdx.x * 4;
    float4 v = *(const float4*)(src + off);
    union { ushort u[4]; short4 s4; } p;
    p.u[0] = f2b(v.x); p.u[1] = f2b(v.y); p.u[2] = f2b(v.z); p.u[3] = f2b(v.w);
    *(short4*)(out + (size_t)m * 65536 + off) = p.s4;
}

// ---------------------------------------------------------------------------
// Bitpack mask[x][y][z] (int32, 16384 rows x 128) -> 128 bits per row.
// P [x*128+y] : z-bits of mask[x][y][:]   (PASS1 reads P[fixed*128 + row])
// PT[y*128+x] : same value, transposed    (PASS0 reads PT[fixed*128 + row])
// One wave per row; ballot packs 64 lanes/call.
// ---------------------------------------------------------------------------
__global__ __launch_bounds__(256) void pack_mask(const int* __restrict__ mask,
                                                 ulonglong2* __restrict__ P,
                                                 ulonglong2* __restrict__ PT) {
    const int row = blockIdx.x * 4 + (threadIdx.x >> 6); // 0..16383
    const int lane = threadIdx.x & 63;
    const int* mrow = mask + (size_t)row * 128;
    unsigned long long lo = __ballot(mrow[lane] != 0);
    unsigned long long hi = __ballot(mrow[64 + lane] != 0);
    if (lane == 0) {
        ulonglong2 v; v.x = lo; v.y = hi;
        P[row] = v;
        PT[(row & 127) * 128 + (row >> 7)] = v;
    }
}

// ---------------------------------------------------------------------------
// C[M][256] = A[M][256] @ W[256][256]^T via mfma 16x16x32 bf16.
// BM=32, BN=256, BK=64, 512 threads = 8 waves (wave w owns cols [w*32,+32)).
// AF32: A is f32, reg-staged with cvt into swizzled LDS. else bf16 via GLDS.
// LDS rows 128 B, XOR-swizzled ((row&7)<<4); W staged with global_load_lds
// using inverse-swizzled source (both-sides-or-neither).
// ---------------------------------------------------------------------------
template <bool AF32, bool OBF16, bool BATCHED>
__global__ __launch_bounds__(512) void gemm2(const void* __restrict__ A0,
                                             const void* __restrict__ A1,
                                             const void* __restrict__ A2,
                                             const ushort* __restrict__ Wbase,
                                             void* __restrict__ Cbase,
                                             float oscale0) {
    __shared__ ushort As[2][32 * 64];    // 4 KB per buf
    __shared__ ushort Ws[2][256 * 64];   // 32 KB per buf
    const int tid = threadIdx.x;
    const int w = tid >> 6, l = tid & 63;
    const int lr = l & 15, g = l >> 4;
    const int row0 = blockIdx.x * 32;

    const void* Ain = A0;
    const ushort* W = Wbase;
    float oscale = oscale0;
    size_t coff = 0;
    if (BATCHED) {
        const int y = blockIdx.y;
        Ain = (y == 0) ? A0 : (y == 1) ? A1 : A2;
        W += (size_t)y * 65536;
        coff = (size_t)y * (M_ROWS * 256);
        oscale = (y == 0) ? oscale0 : 1.0f;
    }

    const int lrow = l >> 3;                    // 0..7 (row within 8-row chunk)
    const int kof = ((l & 7) ^ lrow) * 8;       // inverse-swizzled k offset

    auto stage = [&](int t, int buf) {
        const int kbase = t * 64;
#pragma unroll
        for (int i = 0; i < 4; i++) {
            const int chunk = i * 8 + w;        // 0..31 -> W rows [chunk*8, +8)
            GLDS(W + (size_t)(chunk * 8 + lrow) * 256 + kbase + kof,
                 &Ws[buf][chunk * 512]);
        }
        if (AF32) {
            // 512 threads: 16 threads/row, 4 f32 each -> 4 bf16 (ds_write_b64)
            const float* Af = (const float*)Ain;
            const int r = tid >> 4, k0 = (tid & 15) * 4;
            float4 v = *(const float4*)(Af + (size_t)(row0 + r) * 256 + kbase + k0);
            union { ushort u[4]; short4 s4; } p;
            p.u[0] = f2b(v.x); p.u[1] = f2b(v.y); p.u[2] = f2b(v.z); p.u[3] = f2b(v.w);
            int byte = (r * 128 + k0 * 2) ^ ((r & 7) << 4);
            *(short4*)((char*)&As[buf][0] + byte) = p.s4;
        } else {
            if (w < 4) {                        // A rows [w*8, +8)
                const ushort* Ab = (const ushort*)Ain;
                GLDS(Ab + (size_t)(row0 + w * 8 + lrow) * 256 + kbase + kof,
                     &As[buf][w * 512]);
            }
        }
    };

    f32x4 acc[2][2];
    const f32x4 zero = {0.f, 0.f, 0.f, 0.f};
    acc[0][0] = zero; acc[0][1] = zero; acc[1][0] = zero; acc[1][1] = zero;

    stage(0, 0);
    __syncthreads();

#pragma unroll
    for (int t = 0; t < 4; t++) {
        const int cur = t & 1;
        if (t < 3) stage(t + 1, cur ^ 1);
#pragma unroll
        for (int kk = 0; kk < 2; kk++) {
            bf16x8 a[2], b[2];
#pragma unroll
            for (int fr = 0; fr < 2; fr++) {
                const int r = fr * 16 + lr;
                int byte = r * 128 + kk * 64 + g * 16;
                byte ^= (r & 7) << 4;
                a[fr] = *(const bf16x8*)((const char*)&As[cur][0] + byte);
            }
#pragma unroll
            for (int fc = 0; fc < 2; fc++) {
                const int r = w * 32 + fc * 16 + lr;
                int byte = r * 128 + kk * 64 + g * 16;
                byte ^= (r & 7) << 4;
                b[fc] = *(const bf16x8*)((const char*)&Ws[cur][0] + byte);
            }
#pragma unroll
            for (int fr = 0; fr < 2; fr++)
#pragma unroll
                for (int fc = 0; fc < 2; fc++)
                    acc[fr][fc] = __builtin_amdgcn_mfma_f32_16x16x32_bf16(a[fr], b[fc], acc[fr][fc], 0, 0, 0);
        }
        __syncthreads();
    }

#pragma unroll
    for (int fr = 0; fr < 2; fr++)
#pragma unroll
        for (int fc = 0; fc < 2; fc++)
#pragma unroll
            for (int j = 0; j < 4; j++) {
                const int row = row0 + fr * 16 + g * 4 + j;
                const int col = w * 32 + fc * 16 + lr;
                const float vv = acc[fr][fc][j] * oscale;
                if (OBF16) ((ushort*)Cbase)[coff + (size_t)row * 256 + col] = f2b(vv);
                else       ((float*)Cbase)[(size_t)row * 256 + col] = vv;
            }
}

// ---------------------------------------------------------------------------
// Attention pass. PASS=0: l-half, block=(y,h), rows are x.
//                 PASS=1: r-half + combine, block=(x,h), rows are y.
// Q pre-scaled by 1/sqrt(32). Mask read as prepacked 128-bit rows (2 KB,
// one coalesced load). Q/K LDS pitch 40 ushorts.
// ---------------------------------------------------------------------------
template <int PASS>
__global__ __launch_bounds__(256) void attn_pass(const ushort* __restrict__ qb,
                                                 const ushort* __restrict__ kb,
                                                 const ushort* __restrict__ vb,
                                                 const ulonglong2* __restrict__ Pm,
                                                 float* __restrict__ ml,
                                                 float* __restrict__ sl,
                                                 float* __restrict__ Pl,
                                                 ushort* __restrict__ xb) {
    __shared__ ushort Qs[128 * 40];   // pitch 80 B
    __shared__ ushort Ks[128 * 40];
    __shared__ ushort Vt[32 * 128];   // [d][z], 256B rows, XOR swizzled
    __shared__ ushort Ats[128 * 128]; // [row][z], 256B rows, XOR swizzled
    __shared__ ulonglong2 Ms[128];    // bitpacked mask rows
    __shared__ float mlq[128], slq[128];

    const int tid = threadIdx.x;
    const int fixed = blockIdx.x >> 3; // y (PASS0) or x (PASS1)
    const int h = blockIdx.x & 7;

    int base, stride;
    if (PASS == 0) {
        base = (fixed * NH + h) * DKH;
        stride = N_DIM * NH * DKH;
    } else {
        base = fixed * N_DIM * NH * DKH + h * DKH;
        stride = NH * DKH;
    }

    if (tid < 128) {
        Ms[tid] = Pm[fixed * 128 + tid];
        if (PASS == 1) mlq[tid] = ml[(tid * NH + h) * N_DIM + fixed];
    } else if (PASS == 1) {
        slq[tid - 128] = sl[((tid - 128) * NH + h) * N_DIM + fixed];
    }

    // ---- stage Q, K, Vt (transpose + swizzle) ----
#pragma unroll
    for (int i = 0; i < 2; i++) {
        int idx = tid + i * 256;
        int r = idx >> 2, d0 = (idx & 3) * 8;
        size_t goff = (size_t)base + (size_t)r * stride + d0;
        int4 qv = *(const int4*)(qb + goff);
        *(int4*)&Qs[r * 40 + d0] = qv;
        int4 kv = *(const int4*)(kb + goff);
        *(int4*)&Ks[r * 40 + d0] = kv;
        union { int4 v4; ushort u[8]; } uu;
        uu.v4 = *(const int4*)(vb + goff);
#pragma unroll
        for (int j = 0; j < 8; j++) {
            int d = d0 + j;
            int byte = d * 256 + r * 2;
            byte ^= (d & 7) << 4;
            Vt[byte >> 1] = uu.u[j];
        }
    }
    __syncthreads();

    const int w = tid >> 6;
    const int lane = tid & 63;
    const int lr = lane & 15;
    const int g = lane >> 4;
    const int rbase = w * 32;

    // ---- S = Q K^T (Q pre-scaled) ----
    bf16x8 aq[2];
#pragma unroll
    for (int fr = 0; fr < 2; fr++)
        aq[fr] = *(const bf16x8*)&Qs[(rbase + fr * 16 + lr) * 40 + g * 8];

    f32x4 s[2][8];
    const f32x4 zero = {0.f, 0.f, 0.f, 0.f};
#pragma unroll
    for (int fc = 0; fc < 8; fc++) {
        bf16x8 bk = *(const bf16x8*)&Ks[(fc * 16 + lr) * 40 + g * 8];
#pragma unroll
        for (int fr = 0; fr < 2; fr++)
            s[fr][fc] = __builtin_amdgcn_mfma_f32_16x16x32_bf16(aq[fr], bk, zero, 0, 0, 0);
    }

    // ---- mask (bitpacked), row max, exp, row sum, att->LDS(bf16) ----
    float mx[2][4], sm[2][4];
#pragma unroll
    for (int fr = 0; fr < 2; fr++) {
#pragma unroll
        for (int j = 0; j < 4; j++) {
            const int row = rbase + fr * 16 + g * 4 + j;
            const ulonglong2 mb = Ms[row];
            const unsigned long long mls = mb.x >> lr;
            const unsigned long long mhs = mb.y >> lr;
            float mmax = -3.0e38f;
#pragma unroll
            for (int fc = 0; fc < 8; fc++) {
                const int bit = (int)(((fc < 4 ? mls : mhs) >> ((fc & 3) * 16)) & 1ull);
                float val = bit ? -1.0e9f : s[fr][fc][j];
                s[fr][fc][j] = val;
                mmax = fmaxf(mmax, val);
            }
            mmax = fmaxf(mmax, __shfl_xor(mmax, 1));
            mmax = fmaxf(mmax, __shfl_xor(mmax, 2));
            mmax = fmaxf(mmax, __shfl_xor(mmax, 4));
            mmax = fmaxf(mmax, __shfl_xor(mmax, 8));
            float ssum = 0.f;
#pragma unroll
            for (int fc = 0; fc < 8; fc++) {
                const int col = fc * 16 + lr;
                float e = __expf(s[fr][fc][j] - mmax);
                ssum += e;
                int byte = row * 256 + col * 2;
                byte ^= (row & 7) << 4;
                Ats[byte >> 1] = f2b(e);
            }
            ssum += __shfl_xor(ssum, 1);
            ssum += __shfl_xor(ssum, 2);
            ssum += __shfl_xor(ssum, 4);
            ssum += __shfl_xor(ssum, 8);
            mx[fr][j] = mmax;
            sm[fr][j] = ssum;
        }
    }
    __syncthreads();

    // ---- P = att @ V ----
    f32x4 p[2][2];
    p[0][0] = zero; p[0][1] = zero; p[1][0] = zero; p[1][1] = zero;
#pragma unroll
    for (int ks = 0; ks < 4; ks++) {
        bf16x8 pa[2];
#pragma unroll
        for (int fr = 0; fr < 2; fr++) {
            const int row = rbase + fr * 16 + lr;
            int byte = row * 256 + ks * 64 + g * 16;
            byte ^= (row & 7) << 4;
            pa[fr] = *(const bf16x8*)&Ats[byte >> 1];
        }
#pragma unroll
        for (int fc = 0; fc < 2; fc++) {
            const int rd = fc * 16 + lr;
            int byte = rd * 256 + ks * 64 + g * 16;
            byte ^= (rd & 7) << 4;
            bf16x8 vbf = *(const bf16x8*)&Vt[byte >> 1];
#pragma unroll
            for (int fr = 0; fr < 2; fr++)
                p[fr][fc] = __builtin_amdgcn_mfma_f32_16x16x32_bf16(pa[fr], vbf, p[fr][fc], 0, 0, 0);
        }
    }

    // ---- epilogue ----
    if (PASS == 0) {
#pragma unroll
        for (int fr = 0; fr < 2; fr++) {
#pragma unroll
            for (int j = 0; j < 4; j++) {
                const int row = rbase + fr * 16 + g * 4 + j;
                if (lr == 0) {
                    ml[(fixed * NH + h) * N_DIM + row] = mx[fr][j];
                    sl[(fixed * NH + h) * N_DIM + row] = sm[fr][j];
                }
#pragma unroll
                for (int fc = 0; fc < 2; fc++) {
                    const int d = fc * 16 + lr;
                    Pl[((size_t)(fixed * NH + h) * N_DIM + row) * DKH + d] = p[fr][fc][j];
                }
            }
        }
    } else {
#pragma unroll
        for (int fr = 0; fr < 2; fr++) {
#pragma unroll
            for (int j = 0; j < 4; j++) {
                const int row = rbase + fr * 16 + g * 4 + j;
                const float mr = mx[fr][j], sr = sm[fr][j];
                const float mlv = mlq[row], slv = slq[row];
                const float m = fmaxf(mr, mlv);
                const float cr = __expf(mr - m), cl = __expf(mlv - m);
                const float inv = 1.0f / (sr * cr + slv * cl);
#pragma unroll
                for (int fc = 0; fc < 2; fc++) {
                    const int d = fc * 16 + lr;
                    const float plv = Pl[((size_t)(row * NH + h) * N_DIM + fixed) * DKH + d];
                    const float o = (p[fr][fc][j] * cr + plv * cl) * inv;
                    xb[((size_t)fixed * N_DIM + row) * 256 + h * DKH + d] = f2b(o);
                }
            }
        }
    }
}

extern "C" void kernel_launch(void* const* d_in, const int* in_sizes, int n_in,
                              void* d_out, int out_size, void* d_ws, size_t ws_size,
                              hipStream_t stream) {
    const float* query = (const float*)d_in[0];
    const float* key_t = (const float*)d_in[1];
    const float* value = (const float*)d_in[2];
    const int*   mask  = (const int*)d_in[3];
    const float* Wq    = (const float*)d_in[4];
    const float* Wk    = (const float*)d_in[5];
    const float* Wv    = (const float*)d_in[6];
    const float* Wo    = (const float*)d_in[7];

    const size_t MB = 1024 * 1024;
    char* ws = (char*)d_ws;
    ushort*     qb = (ushort*)ws;                       // 24 MB: q/k/v contiguous
    ushort*     kb = qb + (size_t)M_ROWS * 256;
    ushort*     vb = kb + (size_t)M_ROWS * 256;
    ushort*     xb = (ushort*)(ws + 24 * MB);           // 8 MB
    float*      Pl = (float*)(ws + 32 * MB);            // 16 MB
    float*      ml = (float*)(ws + 48 * MB);            // 512 KB
    float*      sl = (float*)(ws + 48 * MB + 512 * 1024);
    ushort*     Wb = (ushort*)(ws + 49 * MB);           // 512 KB
    ulonglong2* Pp = (ulonglong2*)(ws + 50 * MB);       // 256 KB  [x][y]
    ulonglong2* PT = (ulonglong2*)(ws + 50 * MB + 256 * 1024); // 256 KB [y][x]

    const float qscale = 0.17677669529663687f; // 1/sqrt(32)

    cvt_w_kernel<<<256, 256, 0, stream>>>(Wq, Wk, Wv, Wo, Wb);
    pack_mask<<<4096, 256, 0, stream>>>(mask, Pp, PT);
    gemm2<true, true, true><<<dim3(M_ROWS / 32, 3), 512, 0, stream>>>(
        query, key_t, value, Wb, qb, qscale);
    attn_pass<0><<<N_DIM * NH, 256, 0, stream>>>(qb, kb, vb, PT, ml, sl, Pl, xb);
    attn_pass<1><<<N_DIM * NH, 256, 0, stream>>>(qb, kb, vb, Pp, ml, sl, Pl, xb);
    gemm2<false, false, false><<<dim3(M_ROWS / 32, 1), 512, 0, stream>>>(
        xb, nullptr, nullptr, Wb + 3 * 65536, d_out, 1.0f);
}

// Round 7
// 167.003 us; speedup vs baseline: 1.2715x; 1.0136x over previous
//
#include <hip/hip_runtime.h>
#include <hip/hip_bf16.h>
#include <math.h>

#define N_DIM 128
#define NH 8
#define DKH 32
#define M_ROWS (N_DIM * N_DIM) // 16384

typedef __attribute__((ext_vector_type(8))) short bf16x8;
typedef __attribute__((ext_vector_type(4))) float f32x4;

__device__ inline ushort f2b(float x) {
    union { __hip_bfloat16 b; ushort u; } c;
    c.b = __float2bfloat16(x);
    return c.u;
}

#define GLDS(src, dst) \
    __builtin_amdgcn_global_load_lds((const __attribute__((address_space(1))) void*)(src), \
                                     (__attribute__((address_space(3))) void*)(dst), 16, 0, 0)

// ---------------------------------------------------------------------------
// prep: blocks [0,4096) bitpack the mask; blocks [4096,4352) convert weights.
// P [x*128+y] : z-bits of mask[x][y][:]   (PASS1 reads P[fixed*128 + row])
// PT[y*128+x] : same value, transposed    (PASS0 reads PT[fixed*128 + row])
// ---------------------------------------------------------------------------
__global__ __launch_bounds__(256) void prep_kernel(const int* __restrict__ mask,
                                                   ulonglong2* __restrict__ P,
                                                   ulonglong2* __restrict__ PT,
                                                   const float* __restrict__ w0,
                                                   const float* __restrict__ w1,
                                                   const float* __restrict__ w2,
                                                   const float* __restrict__ w3,
                                                   ushort* __restrict__ wout) {
    if (blockIdx.x < 4096) {
        const int row = blockIdx.x * 4 + (threadIdx.x >> 6); // 0..16383
        const int lane = threadIdx.x & 63;
        const int* mrow = mask + (size_t)row * 128;
        unsigned long long lo = __ballot(mrow[lane] != 0);
        unsigned long long hi = __ballot(mrow[64 + lane] != 0);
        if (lane == 0) {
            ulonglong2 v; v.x = lo; v.y = hi;
            P[row] = v;
            PT[(row & 127) * 128 + (row >> 7)] = v;
        }
    } else {
        const int b = blockIdx.x - 4096;   // 0..255
        const int m = b >> 6;
        const float* src = (m == 0) ? w0 : (m == 1) ? w1 : (m == 2) ? w2 : w3;
        const int off = (b & 63) * 1024 + threadIdx.x * 4;
        float4 v = *(const float4*)(src + off);
        union { ushort u[4]; short4 s4; } p;
        p.u[0] = f2b(v.x); p.u[1] = f2b(v.y); p.u[2] = f2b(v.z); p.u[3] = f2b(v.w);
        *(short4*)(wout + (size_t)m * 65536 + off) = p.s4;
    }
}

// ---------------------------------------------------------------------------
// C[M][256] = A[M][256] @ W[256][256]^T via mfma 16x16x32 bf16.
// BM=32, BN=256, BK=64, 512 threads = 8 waves (wave w owns cols [w*32,+32)).
// AF32: A is f32, reg-staged with cvt into swizzled LDS. else bf16 via GLDS.
// LDS rows 128 B, XOR-swizzled ((row&7)<<4); W staged with global_load_lds
// using inverse-swizzled source (both-sides-or-neither).
// ---------------------------------------------------------------------------
template <bool AF32, bool OBF16, bool BATCHED>
__global__ __launch_bounds__(512) void gemm2(const void* __restrict__ A0,
                                             const void* __restrict__ A1,
                                             const void* __restrict__ A2,
                                             const ushort* __restrict__ Wbase,
                                             void* __restrict__ Cbase,
                                             float oscale0) {
    __shared__ ushort As[2][32 * 64];    // 4 KB per buf
    __shared__ ushort Ws[2][256 * 64];   // 32 KB per buf
    const int tid = threadIdx.x;
    const int w = tid >> 6, l = tid & 63;
    const int lr = l & 15, g = l >> 4;
    const int row0 = blockIdx.x * 32;

    const void* Ain = A0;
    const ushort* W = Wbase;
    float oscale = oscale0;
    size_t coff = 0;
    if (BATCHED) {
        const int y = blockIdx.y;
        Ain = (y == 0) ? A0 : (y == 1) ? A1 : A2;
        W += (size_t)y * 65536;
        coff = (size_t)y * (M_ROWS * 256);
        oscale = (y == 0) ? oscale0 : 1.0f;
    }

    const int lrow = l >> 3;                    // 0..7 (row within 8-row chunk)
    const int kof = ((l & 7) ^ lrow) * 8;       // inverse-swizzled k offset

    auto stage = [&](int t, int buf) {
        const int kbase = t * 64;
#pragma unroll
        for (int i = 0; i < 4; i++) {
            const int chunk = i * 8 + w;        // 0..31 -> W rows [chunk*8, +8)
            GLDS(W + (size_t)(chunk * 8 + lrow) * 256 + kbase + kof,
                 &Ws[buf][chunk * 512]);
        }
        if (AF32) {
            // 512 threads: 16 threads/row, 4 f32 each -> 4 bf16 (ds_write_b64)
            const float* Af = (const float*)Ain;
            const int r = tid >> 4, k0 = (tid & 15) * 4;
            float4 v = *(const float4*)(Af + (size_t)(row0 + r) * 256 + kbase + k0);
            union { ushort u[4]; short4 s4; } p;
            p.u[0] = f2b(v.x); p.u[1] = f2b(v.y); p.u[2] = f2b(v.z); p.u[3] = f2b(v.w);
            int byte = (r * 128 + k0 * 2) ^ ((r & 7) << 4);
            *(short4*)((char*)&As[buf][0] + byte) = p.s4;
        } else {
            if (w < 4) {                        // A rows [w*8, +8)
                const ushort* Ab = (const ushort*)Ain;
                GLDS(Ab + (size_t)(row0 + w * 8 + lrow) * 256 + kbase + kof,
                     &As[buf][w * 512]);
            }
        }
    };

    f32x4 acc[2][2];
    const f32x4 zero = {0.f, 0.f, 0.f, 0.f};
    acc[0][0] = zero; acc[0][1] = zero; acc[1][0] = zero; acc[1][1] = zero;

    stage(0, 0);
    __syncthreads();

#pragma unroll
    for (int t = 0; t < 4; t++) {
        const int cur = t & 1;
        if (t < 3) stage(t + 1, cur ^ 1);
#pragma unroll
        for (int kk = 0; kk < 2; kk++) {
            bf16x8 a[2], b[2];
#pragma unroll
            for (int fr = 0; fr < 2; fr++) {
                const int r = fr * 16 + lr;
                int byte = r * 128 + kk * 64 + g * 16;
                byte ^= (r & 7) << 4;
                a[fr] = *(const bf16x8*)((const char*)&As[cur][0] + byte);
            }
#pragma unroll
            for (int fc = 0; fc < 2; fc++) {
                const int r = w * 32 + fc * 16 + lr;
                int byte = r * 128 + kk * 64 + g * 16;
                byte ^= (r & 7) << 4;
                b[fc] = *(const bf16x8*)((const char*)&Ws[cur][0] + byte);
            }
#pragma unroll
            for (int fr = 0; fr < 2; fr++)
#pragma unroll
                for (int fc = 0; fc < 2; fc++)
                    acc[fr][fc] = __builtin_amdgcn_mfma_f32_16x16x32_bf16(a[fr], b[fc], acc[fr][fc], 0, 0, 0);
        }
        __syncthreads();
    }

#pragma unroll
    for (int fr = 0; fr < 2; fr++)
#pragma unroll
        for (int fc = 0; fc < 2; fc++)
#pragma unroll
            for (int j = 0; j < 4; j++) {
                const int row = row0 + fr * 16 + g * 4 + j;
                const int col = w * 32 + fc * 16 + lr;
                const float vv = acc[fr][fc][j] * oscale;
                if (OBF16) ((ushort*)Cbase)[coff + (size_t)row * 256 + col] = f2b(vv);
                else       ((float*)Cbase)[(size_t)row * 256 + col] = vv;
            }
}

// ---------------------------------------------------------------------------
// Attention pass. PASS=0: l-half, block=(y,h), rows are x.
//                 PASS=1: r-half + combine, block=(x,h), rows are y.
// Q pre-scaled by 1/sqrt(32), loaded global->reg (no LDS). Mask prepacked.
// Pl/ml/sl all stored in [x][h][y(,d)] layout: PASS0 scatter-writes,
// PASS1 reads contiguously (Pl loads issued at kernel start).
// ---------------------------------------------------------------------------
template <int PASS>
__global__ __launch_bounds__(256) void attn_pass(const ushort* __restrict__ qb,
                                                 const ushort* __restrict__ kb,
                                                 const ushort* __restrict__ vb,
                                                 const ulonglong2* __restrict__ Pm,
                                                 float* __restrict__ ml,
                                                 float* __restrict__ sl,
                                                 float* __restrict__ Pl,
                                                 ushort* __restrict__ xb) {
    __shared__ ushort Ks[128 * 40];   // pitch 80 B
    __shared__ ushort Vt[32 * 128];   // [d][z], 256B rows, XOR swizzled
    __shared__ ushort Ats[128 * 128]; // [row][z], 256B rows, XOR swizzled
    __shared__ ulonglong2 Ms[128];    // bitpacked mask rows
    __shared__ float mlq[128], slq[128];

    const int tid = threadIdx.x;
    const int fixed = blockIdx.x >> 3; // y (PASS0) or x (PASS1)
    const int h = blockIdx.x & 7;

    int base, stride;
    if (PASS == 0) {
        base = (fixed * NH + h) * DKH;
        stride = N_DIM * NH * DKH;
    } else {
        base = fixed * N_DIM * NH * DKH + h * DKH;
        stride = NH * DKH;
    }

    const int w = tid >> 6;
    const int lane = tid & 63;
    const int lr = lane & 15;
    const int g = lane >> 4;
    const int rbase = w * 32;

    // ---- early: mask bits, pass-0 stats, Pl prefetch, Q frags ----
    if (tid < 128) {
        Ms[tid] = Pm[fixed * 128 + tid];
        if (PASS == 1) mlq[tid] = ml[(fixed * NH + h) * N_DIM + tid];
    } else if (PASS == 1) {
        slq[tid - 128] = sl[(fixed * NH + h) * N_DIM + (tid - 128)];
    }

    float plv[2][2][4];
    if (PASS == 1) {
#pragma unroll
        for (int fr = 0; fr < 2; fr++)
#pragma unroll
            for (int j = 0; j < 4; j++) {
                const int row = rbase + fr * 16 + g * 4 + j;
#pragma unroll
                for (int fc = 0; fc < 2; fc++) {
                    const int d = fc * 16 + lr;
                    plv[fr][fc][j] = Pl[((size_t)(fixed * NH + h) * N_DIM + row) * DKH + d];
                }
            }
    }

    bf16x8 aq[2];
#pragma unroll
    for (int fr = 0; fr < 2; fr++)
        aq[fr] = *(const bf16x8*)(qb + (size_t)base +
                                  (size_t)(rbase + fr * 16 + lr) * stride + g * 8);

    // ---- stage K, Vt (transpose + swizzle) ----
#pragma unroll
    for (int i = 0; i < 2; i++) {
        int idx = tid + i * 256;
        int r = idx >> 2, d0 = (idx & 3) * 8;
        size_t goff = (size_t)base + (size_t)r * stride + d0;
        int4 kv = *(const int4*)(kb + goff);
        *(int4*)&Ks[r * 40 + d0] = kv;
        union { int4 v4; ushort u[8]; } uu;
        uu.v4 = *(const int4*)(vb + goff);
#pragma unroll
        for (int j = 0; j < 8; j++) {
            int d = d0 + j;
            int byte = d * 256 + r * 2;
            byte ^= (d & 7) << 4;
            Vt[byte >> 1] = uu.u[j];
        }
    }
    __syncthreads();

    // ---- S = Q K^T (Q pre-scaled) ----
    f32x4 s[2][8];
    const f32x4 zero = {0.f, 0.f, 0.f, 0.f};
#pragma unroll
    for (int fc = 0; fc < 8; fc++) {
        bf16x8 bk = *(const bf16x8*)&Ks[(fc * 16 + lr) * 40 + g * 8];
#pragma unroll
        for (int fr = 0; fr < 2; fr++)
            s[fr][fc] = __builtin_amdgcn_mfma_f32_16x16x32_bf16(aq[fr], bk, zero, 0, 0, 0);
    }

    // ---- mask (bitpacked), row max, exp, row sum, att->LDS(bf16) ----
    float mx[2][4], sm[2][4];
#pragma unroll
    for (int fr = 0; fr < 2; fr++) {
#pragma unroll
        for (int j = 0; j < 4; j++) {
            const int row = rbase + fr * 16 + g * 4 + j;
            const ulonglong2 mb = Ms[row];
            const unsigned long long mls = mb.x >> lr;
            const unsigned long long mhs = mb.y >> lr;
            float mmax = -3.0e38f;
#pragma unroll
            for (int fc = 0; fc < 8; fc++) {
                const int bit = (int)(((fc < 4 ? mls : mhs) >> ((fc & 3) * 16)) & 1ull);
                float val = bit ? -1.0e9f : s[fr][fc][j];
                s[fr][fc][j] = val;
                mmax = fmaxf(mmax, val);
            }
            mmax = fmaxf(mmax, __shfl_xor(mmax, 1));
            mmax = fmaxf(mmax, __shfl_xor(mmax, 2));
            mmax = fmaxf(mmax, __shfl_xor(mmax, 4));
            mmax = fmaxf(mmax, __shfl_xor(mmax, 8));
            float ssum = 0.f;
#pragma unroll
            for (int fc = 0; fc < 8; fc++) {
                const int col = fc * 16 + lr;
                float e = __expf(s[fr][fc][j] - mmax);
                ssum += e;
                int byte = row * 256 + col * 2;
                byte ^= (row & 7) << 4;
                Ats[byte >> 1] = f2b(e);
            }
            ssum += __shfl_xor(ssum, 1);
            ssum += __shfl_xor(ssum, 2);
            ssum += __shfl_xor(ssum, 4);
            ssum += __shfl_xor(ssum, 8);
            mx[fr][j] = mmax;
            sm[fr][j] = ssum;
        }
    }
    __syncthreads();

    // ---- P = att @ V ----
    f32x4 p[2][2];
    p[0][0] = zero; p[0][1] = zero; p[1][0] = zero; p[1][1] = zero;
#pragma unroll
    for (int ks = 0; ks < 4; ks++) {
        bf16x8 pa[2];
#pragma unroll
        for (int fr = 0; fr < 2; fr++) {
            const int row = rbase + fr * 16 + lr;
            int byte = row * 256 + ks * 64 + g * 16;
            byte ^= (row & 7) << 4;
            pa[fr] = *(const bf16x8*)&Ats[byte >> 1];
        }
#pragma unroll
        for (int fc = 0; fc < 2; fc++) {
            const int rd = fc * 16 + lr;
            int byte = rd * 256 + ks * 64 + g * 16;
            byte ^= (rd & 7) << 4;
            bf16x8 vbf = *(const bf16x8*)&Vt[byte >> 1];
#pragma unroll
            for (int fr = 0; fr < 2; fr++)
                p[fr][fc] = __builtin_amdgcn_mfma_f32_16x16x32_bf16(pa[fr], vbf, p[fr][fc], 0, 0, 0);
        }
    }

    // ---- epilogue ----
    if (PASS == 0) {
        // scatter-store stats/PV in PASS1-friendly layout [x][h][y(,d)]
#pragma unroll
        for (int fr = 0; fr < 2; fr++) {
#pragma unroll
            for (int j = 0; j < 4; j++) {
                const int row = rbase + fr * 16 + g * 4 + j;   // x
                if (lr == 0) {
                    ml[((size_t)row * NH + h) * N_DIM + fixed] = mx[fr][j];
                    sl[((size_t)row * NH + h) * N_DIM + fixed] = sm[fr][j];
                }
#pragma unroll
                for (int fc = 0; fc < 2; fc++) {
                    const int d = fc * 16 + lr;
                    Pl[((size_t)(row * NH + h) * N_DIM + fixed) * DKH + d] = p[fr][fc][j];
                }
            }
        }
    } else {
#pragma unroll
        for (int fr = 0; fr < 2; fr++) {
#pragma unroll
            for (int j = 0; j < 4; j++) {
                const int row = rbase + fr * 16 + g * 4 + j;   // y
                const float mr = mx[fr][j], sr = sm[fr][j];
                const float mlv = mlq[row], slv = slq[row];
                const float m = fmaxf(mr, mlv);
                const float cr = __expf(mr - m), cl = __expf(mlv - m);
                const float inv = 1.0f / (sr * cr + slv * cl);
#pragma unroll
                for (int fc = 0; fc < 2; fc++) {
                    const int d = fc * 16 + lr;
                    const float o = (p[fr][fc][j] * cr + plv[fr][fc][j] * cl) * inv;
                    xb[((size_t)fixed * N_DIM + row) * 256 + h * DKH + d] = f2b(o);
                }
            }
        }
    }
}

extern "C" void kernel_launch(void* const* d_in, const int* in_sizes, int n_in,
                              void* d_out, int out_size, void* d_ws, size_t ws_size,
                              hipStream_t stream) {
    const float* query = (const float*)d_in[0];
    const float* key_t = (const float*)d_in[1];
    const float* value = (const float*)d_in[2];
    const int*   mask  = (const int*)d_in[3];
    const float* Wq    = (const float*)d_in[4];
    const float* Wk    = (const float*)d_in[5];
    const float* Wv    = (const float*)d_in[6];
    const float* Wo    = (const float*)d_in[7];

    const size_t MB = 1024 * 1024;
    char* ws = (char*)d_ws;
    ushort*     qb = (ushort*)ws;                       // 24 MB: q/k/v contiguous
    ushort*     kb = qb + (size_t)M_ROWS * 256;
    ushort*     vb = kb + (size_t)M_ROWS * 256;
    ushort*     xb = (ushort*)(ws + 24 * MB);           // 8 MB
    float*      Pl = (float*)(ws + 32 * MB);            // 16 MB
    float*      ml = (float*)(ws + 48 * MB);            // 512 KB
    float*      sl = (float*)(ws + 48 * MB + 512 * 1024);
    ushort*     Wb = (ushort*)(ws + 49 * MB);           // 512 KB
    ulonglong2* Pp = (ulonglong2*)(ws + 50 * MB);       // 256 KB  [x][y]
    ulonglong2* PT = (ulonglong2*)(ws + 50 * MB + 256 * 1024); // 256 KB [y][x]

    const float qscale = 0.17677669529663687f; // 1/sqrt(32)

    prep_kernel<<<4352, 256, 0, stream>>>(mask, Pp, PT, Wq, Wk, Wv, Wo, Wb);
    gemm2<true, true, true><<<dim3(M_ROWS / 32, 3), 512, 0, stream>>>(
        query, key_t, value, Wb, qb, qscale);
    attn_pass<0><<<N_DIM * NH, 256, 0, stream>>>(qb, kb, vb, PT, ml, sl, Pl, xb);
    attn_pass<1><<<N_DIM * NH, 256, 0, stream>>>(qb, kb, vb, Pp, ml, sl, Pl, xb);
    gemm2<false, false, false><<<dim3(M_ROWS / 32, 1), 512, 0, stream>>>(
        xb, nullptr, nullptr, Wb + 3 * 65536, d_out, 1.0f);
}